// Round 2
// baseline (858.265 us; speedup 1.0000x reference)
//
#include <hip/hip_runtime.h>

// Problem constants (fixed by the reference)
#define B_  4
#define SQ_ 4096
#define SK_ 462
#define H_  10
#define DH_ 64
#define D_  (H_ * DH_)   // 640
#define KT_ 15           // ceil(462/32)

typedef _Float16 half8  __attribute__((ext_vector_type(8)));
typedef _Float16 half4v __attribute__((ext_vector_type(4)));
typedef _Float16 half2v __attribute__((ext_vector_type(2)));
typedef float    floatx4 __attribute__((ext_vector_type(4)));

// ---------------------------------------------------------------------------
// mask_bool storage-format detection: 0=int32, 1=byte, 2=float32 per element.
// (R1 FETCH_SIZE=426MB matched byte-format; keep runtime detection for safety.)
// ---------------------------------------------------------------------------
__global__ void detect_mask_fmt(const unsigned int* __restrict__ mb_dw,
                                int* __restrict__ flag) {
  __shared__ int s_float, s_byte;
  if (threadIdx.x == 0) { s_float = 0; s_byte = 0; }
  __syncthreads();
  int fl = 0, by = 0;
  for (int i = threadIdx.x; i < 1024; i += 256) {
    unsigned int x = mb_dw[i];
    if (x > 1u) {
      if (x == 0x3F800000u) fl = 1; else by = 1;
    }
  }
  if (fl) atomicOr(&s_float, 1);
  if (by) atomicOr(&s_byte, 1);
  __syncthreads();
  if (threadIdx.x == 0) flag[0] = s_float ? 2 : (s_byte ? 1 : 0);
}

// ---------------------------------------------------------------------------
// Flash-style masked cross attention, software-pipelined.
// grid=(64,H,B), block=256 (4 waves), wave owns 16 query rows.
// mfma_f32_16x16x32_f16 layouts: A[m=l16][k=g4*8+j], B[k=g4*8+j][n=l16],
// C/D: col=l16, row=g4*4+reg.
// Pipeline: iter kt issues global K/V+mask loads for kt+1 (kv first so the
// vmcnt FIFO wait at the LDS store leaves mask loads in flight); ONE raw
// s_barrier per iter (lgkmcnt(0) only — register-destined global prefetches
// are NOT drained, unlike compiler __syncthreads which emits vmcnt(0)).
// LDS: K in exact B-frag order (conflict-free b128), V row-major f16 read as
// 8x ds_read_u16 (0-conflict: banks (16g4+8nt+j+l16/2)%32 cover all 32 once).
// ---------------------------------------------------------------------------
__global__ __launch_bounds__(256)
void attn_fwd(const float* __restrict__ q, const float* __restrict__ k,
              const float* __restrict__ v, const void* __restrict__ mb,
              const float* __restrict__ msc, float* __restrict__ out,
              const int* __restrict__ flag) {
  // 8192 + 8448 + 4096 = 20736 B -> 7 blocks/CU by LDS
  __shared__ __align__(16) _Float16 ksf[2][2048];     // [buf][frag-order] 4 frags x 64 lanes x 8
  __shared__ __align__(16) _Float16 vsf[2][32 * 66];  // [buf][key][dim], stride 66 halves
  __shared__ __align__(16) _Float16 psf[4][512];      // per-wave P relayout, frag order

  const int tid  = threadIdx.x;
  const int wave = tid >> 6;
  const int lane = tid & 63;
  const int l16  = lane & 15;
  const int g4   = lane >> 4;

  const int b  = blockIdx.z;
  const int h  = blockIdx.y;
  const int q0 = blockIdx.x * 64;
  const int fmt = flag[0];

  const float* kbase = k + (size_t)b * SK_ * D_ + h * DH_;
  const float* vbase = v + (size_t)b * SK_ * D_ + h * DH_;
  const unsigned char* mb_b = (const unsigned char*)mb;
  const int*   mb_i = (const int*)mb;
  const float* mb_f = (const float*)mb;

  // staging-thread geometry (2 quarters of the 32x64 K/V chunk per thread)
  int skey[2], sd4[2], wkf[2], wlw[2], wsub[2];
  #pragma unroll
  for (int i = 0; i < 2; ++i) {
    int idx4 = tid + i * 256;
    skey[i] = idx4 >> 4;           // 0..31
    sd4[i]  = (idx4 & 15) * 4;     // 0..60
    int ct = skey[i] >> 4, kk = sd4[i] >> 5, oct = (sd4[i] & 31) >> 3;
    wkf[i]  = ct * 2 + kk;
    wlw[i]  = (skey[i] & 15) + 16 * oct;
    wsub[i] = sd4[i] & 7;          // 0 or 4
  }

  // ---- Q A-frags straight from global (no LDS round-trip) ----
  half8 aq[2];
  {
    const float* qp = q + ((size_t)(b * SQ_) + q0 + wave * 16 + l16) * D_ + h * DH_;
    #pragma unroll
    for (int kk = 0; kk < 2; ++kk) {
      float4 f0 = *(const float4*)(qp + kk * 32 + g4 * 8);
      float4 f1 = *(const float4*)(qp + kk * 32 + g4 * 8 + 4);
      aq[kk][0] = (_Float16)f0.x; aq[kk][1] = (_Float16)f0.y;
      aq[kk][2] = (_Float16)f0.z; aq[kk][3] = (_Float16)f0.w;
      aq[kk][4] = (_Float16)f1.x; aq[kk][5] = (_Float16)f1.y;
      aq[kk][6] = (_Float16)f1.z; aq[kk][7] = (_Float16)f1.w;
    }
  }

  const unsigned rowbase =
      (unsigned)((b * H_ + h) * SQ_ + q0 + wave * 16 + g4 * 4) * (unsigned)SK_;

  auto kv_load = [&](int kt, float4* kr, float4* vr, int* ok) {
    #pragma unroll
    for (int i = 0; i < 2; ++i) {
      int gk  = kt * 32 + skey[i];
      int gkc = gk < SK_ ? gk : SK_ - 1;
      ok[i]   = gk < SK_;
      kr[i] = *(const float4*)(kbase + (size_t)gkc * D_ + sd4[i]);
      vr[i] = *(const float4*)(vbase + (size_t)gkc * D_ + sd4[i]);
    }
  };

  auto mask_load = [&](int kt, float* mv, unsigned& mok) {
    mok = 0u;
    #pragma unroll
    for (int ct = 0; ct < 2; ++ct) {
      int col   = kt * 32 + ct * 16 + l16;
      int cc    = col < SK_ ? col : SK_ - 1;
      int valid = col < SK_;
      #pragma unroll
      for (int r = 0; r < 4; ++r) {
        unsigned idx = rowbase + (unsigned)(r * SK_) + (unsigned)cc;
        mv[ct * 4 + r] = msc[idx];
        int on;
        if (fmt == 1)      on = mb_b[idx] != 0;
        else if (fmt == 0) on = mb_i[idx] != 0;
        else               on = mb_f[idx] != 0.0f;
        if (valid && on) mok |= 1u << (ct * 4 + r);
      }
    }
  };

  auto kv_store = [&](int buf, const float4* kr, const float4* vr, const int* ok) {
    #pragma unroll
    for (int i = 0; i < 2; ++i) {
      half4v kh;
      kh[0] = (_Float16)kr[i].x; kh[1] = (_Float16)kr[i].y;
      kh[2] = (_Float16)kr[i].z; kh[3] = (_Float16)kr[i].w;
      *(half4v*)&ksf[buf][(wkf[i] * 64 + wlw[i]) * 8 + wsub[i]] = kh;
      // V padding MUST be zero (NaN*0 would poison the accumulator)
      float fx = ok[i] ? vr[i].x : 0.0f, fy = ok[i] ? vr[i].y : 0.0f;
      float fz = ok[i] ? vr[i].z : 0.0f, fw = ok[i] ? vr[i].w : 0.0f;
      half2v v01; v01[0] = (_Float16)fx; v01[1] = (_Float16)fy;
      half2v v23; v23[0] = (_Float16)fz; v23[1] = (_Float16)fw;
      *(half2v*)&vsf[buf][skey[i] * 66 + sd4[i]]     = v01;
      *(half2v*)&vsf[buf][skey[i] * 66 + sd4[i] + 2] = v23;
    }
  };

  // ---- accumulators ----
  floatx4 o_acc[4];
  floatx4 l_acc;
  #pragma unroll
  for (int nt = 0; nt < 4; ++nt)
    #pragma unroll
    for (int r = 0; r < 4; ++r) o_acc[nt][r] = 0.0f;
  #pragma unroll
  for (int r = 0; r < 4; ++r) l_acc[r] = 0.0f;
  float m2[4] = {-1e30f, -1e30f, -1e30f, -1e30f};

  half8 ones_f;
  #pragma unroll
  for (int j = 0; j < 8; ++j) ones_f[j] = (_Float16)1.0f;

  const float c2 = 0.18033688011112042f;  // (1/sqrt(64)) * log2(e)

  // ---- prologue: tile 0 ----
  float msc_c[8]; unsigned mok_c;
  {
    float4 kr[2], vr[2]; int ok[2];
    kv_load(0, kr, vr, ok);
    mask_load(0, msc_c, mok_c);
    kv_store(0, kr, vr, ok);
  }
  asm volatile("s_waitcnt lgkmcnt(0)\n\ts_barrier" ::: "memory");

  for (int kt = 0; kt < KT_; ++kt) {
    const int buf = kt & 1;
    const bool hasn = (kt + 1 < KT_);
    float msc_n[8] = {0, 0, 0, 0, 0, 0, 0, 0};
    unsigned mok_n = 0;
    float4 kr[2], vr[2]; int ok[2];
    if (hasn) {
      kv_load(kt + 1, kr, vr, ok);      // kv FIRST: vmcnt FIFO lets the LDS
      mask_load(kt + 1, msc_n, mok_n);  // store drain kv without draining mask
    }

    // ---- S = Q K^T (frag-order LDS, conflict-free b128) ----
    floatx4 s0v = {0.f, 0.f, 0.f, 0.f}, s1v = {0.f, 0.f, 0.f, 0.f};
    #pragma unroll
    for (int kk = 0; kk < 2; ++kk) {
      half8 kb0 = *(const half8*)&ksf[buf][((0 * 2 + kk) * 64 + lane) * 8];
      s0v = __builtin_amdgcn_mfma_f32_16x16x32_f16(aq[kk], kb0, s0v, 0, 0, 0);
      half8 kb1 = *(const half8*)&ksf[buf][((1 * 2 + kk) * 64 + lane) * 8];
      s1v = __builtin_amdgcn_mfma_f32_16x16x32_f16(aq[kk], kb1, s1v, 0, 0, 0);
    }

    // ---- online softmax (base-2) ----
    float pv[2][4], alpha[4];
    #pragma unroll
    for (int r = 0; r < 4; ++r) {
      float s0 = s0v[r] * (c2 * msc_c[r]);
      float s1 = s1v[r] * (c2 * msc_c[4 + r]);
      s0 = ((mok_c >> r) & 1u) ? s0 : -1e30f;
      s1 = ((mok_c >> (4 + r)) & 1u) ? s1 : -1e30f;
      float mx = fmaxf(s0, s1);
      mx = fmaxf(mx, __shfl_xor(mx, 1));
      mx = fmaxf(mx, __shfl_xor(mx, 2));
      mx = fmaxf(mx, __shfl_xor(mx, 4));
      mx = fmaxf(mx, __shfl_xor(mx, 8));
      float mnew = fmaxf(m2[r], mx);
      alpha[r] = exp2f(m2[r] - mnew);
      m2[r] = mnew;
      pv[0][r] = exp2f(s0 - mnew);   // masked: exp2(-huge) == +0
      pv[1][r] = exp2f(s1 - mnew);
    }
    // alphas in (0,1]: product==1 iff all==1 -> uniform rescale-skip
    float aprod = alpha[0] * alpha[1] * alpha[2] * alpha[3];
    if (__any(aprod != 1.0f)) {
      #pragma unroll
      for (int r = 0; r < 4; ++r) {
        l_acc[r] *= alpha[r];
        #pragma unroll
        for (int nt = 0; nt < 4; ++nt) o_acc[nt][r] *= alpha[r];
      }
    }

    // ---- P: C-layout -> A-layout via per-wave frag-order LDS buffer ----
    #pragma unroll
    for (int ct = 0; ct < 2; ++ct)
      #pragma unroll
      for (int r = 0; r < 4; ++r)
        psf[wave][((g4 * 4 + r) + 16 * (ct * 2 + (l16 >> 3))) * 8 + (l16 & 7)] =
            (_Float16)pv[ct][r];
    asm volatile("s_waitcnt lgkmcnt(0)" ::: "memory");  // wave-local w->r
    half8 pa = *(const half8*)&psf[wave][lane * 8];

    // ---- O += P V ; l += rowsum(P) (ones-column MFMA rides same rescale) --
    #pragma unroll
    for (int nt = 0; nt < 4; ++nt) {
      half8 vb;
      #pragma unroll
      for (int j = 0; j < 8; ++j)
        vb[j] = vsf[buf][(g4 * 8 + j) * 66 + nt * 16 + l16];  // 0-conflict u16
      o_acc[nt] = __builtin_amdgcn_mfma_f32_16x16x32_f16(pa, vb, o_acc[nt], 0, 0, 0);
    }
    l_acc = __builtin_amdgcn_mfma_f32_16x16x32_f16(pa, ones_f, l_acc, 0, 0, 0);

    if (hasn) kv_store(buf ^ 1, kr, vr, ok);  // waits vmcnt for kv only

    #pragma unroll
    for (int t = 0; t < 8; ++t) msc_c[t] = msc_n[t];
    mok_c = mok_n;

    // raw barrier: LDS drained, register-destined global prefetches NOT
    asm volatile("s_waitcnt lgkmcnt(0)\n\ts_barrier" ::: "memory");
  }

  // ---- epilogue ----
  #pragma unroll
  for (int r = 0; r < 4; ++r) {
    float inv = 1.0f / l_acc[r];
    int qrow = q0 + wave * 16 + g4 * 4 + r;
    float* ob = out + (size_t)(b * SQ_ + qrow) * D_ + h * DH_;
    #pragma unroll
    for (int nt = 0; nt < 4; ++nt)
      ob[nt * 16 + l16] = o_acc[nt][r] * inv;
  }
}

extern "C" void kernel_launch(void* const* d_in, const int* in_sizes, int n_in,
                              void* d_out, int out_size, void* d_ws, size_t ws_size,
                              hipStream_t stream) {
  const float* q   = (const float*)d_in[0];
  const float* k   = (const float*)d_in[1];
  const float* v   = (const float*)d_in[2];
  const void*  mb  = d_in[3];
  const float* msc = (const float*)d_in[4];
  float* out = (float*)d_out;
  int*   flg = (int*)d_ws;

  detect_mask_fmt<<<1, 256, 0, stream>>>((const unsigned int*)mb, flg);
  dim3 grid(SQ_ / 64, H_, B_);
  attn_fwd<<<grid, 256, 0, stream>>>(q, k, v, mb, msc, out, flg);
}